// Round 8
// baseline (25686.679 us; speedup 1.0000x reference)
//
#include <hip/hip_runtime.h>

#define S_LEN 2048
#define HROW 264          // padded LDS row stride (f16)
#define TBUF (16 * HROW)  // one 16-row tile buffer

typedef _Float16 f16;
typedef _Float16 f16x8 __attribute__((ext_vector_type(8)));
typedef float f32x4 __attribute__((ext_vector_type(4)));
typedef unsigned u32;
typedef unsigned long long u64;

#define PERM_SEL 0x05040100u  // perm(a,b,SEL) = lo16(b) | lo16(a)<<16

__device__ __forceinline__ float sigf(float x) {
  x = fminf(fmaxf(x, -30.f), 30.f);
  float e = __builtin_amdgcn_exp2f(-1.44269504089f * x);
  return __builtin_amdgcn_rcpf(1.f + e);
}
__device__ __forceinline__ float tanh_fast(float x) {
  x = fminf(fmaxf(x, -15.f), 15.f);
  float e = __builtin_amdgcn_exp2f(2.88539008178f * x);  // e^(2x)
  return 1.f - 2.f * __builtin_amdgcn_rcpf(e + 1.f);
}
__device__ __forceinline__ void st_hx(u32* p, u32 v) {
  __hip_atomic_store(p, v, __ATOMIC_RELAXED, __HIP_MEMORY_SCOPE_AGENT);
}
__device__ __forceinline__ u64 ld_hx64(const u64* p) {
  return __hip_atomic_load(p, __ATOMIC_RELAXED, __HIP_MEMORY_SCOPE_AGENT);
}
__device__ __forceinline__ u32 umin2(u32 a, u32 b) { return a < b ? a : b; }

// Build W16[1024][512] = [Whh | Wih] f16, bias = bih + bhh, zero hx tag words.
__global__ void convert_k(const float* __restrict__ Wih, const float* __restrict__ Whh,
                          const float* __restrict__ bih, const float* __restrict__ bhh,
                          f16* __restrict__ W16, float* __restrict__ bias,
                          u32* __restrict__ hx) {
  int i = blockIdx.x * blockDim.x + threadIdx.x;  // 524288 threads
  int n = i >> 9, k = i & 511;
  W16[i] = (f16)((k < 256) ? Whh[n * 256 + k] : Wih[n * 256 + (k - 256)]);
  if (i < 1024) bias[i] = bih[i] + bhh[i];
  if (i < 65536) hx[i] = 0u;  // 4-deep tag buffers; replay safety
}

// Pre-convert embedding table to f16 (8,192,000 elems, 8 per thread).
__global__ void convert_embed_k(const float* __restrict__ e, f16* __restrict__ e16) {
  int i = (blockIdx.x * 256 + threadIdx.x) * 8;
  float4 a = *(const float4*)(e + i);
  float4 b = *(const float4*)(e + i + 4);
  f16x8 v = {(f16)a.x, (f16)a.y, (f16)a.z, (f16)a.w,
             (f16)b.x, (f16)b.y, (f16)b.z, (f16)b.w};
  *(f16x8*)(e16 + i) = v;
}

// Persistent LSTM with 4 STAGGERED chains (round-robin) to hide the MALL RTT.
// 8 wgs = 2 glsets x 4 quarters (64 dims). Each wg serves 32 batches = 4
// chains x 8. Per t, 4 phases: phase(t,c) = {poll chain-c tag t, gather,
// barrier, h-MFMA(c), update+publish tag t+1, window (x staging + xpart(t+1,c))}.
// Chain c's data published at (t-1,c), consumed at (t,c): gap = 3 full phases
// of other chains' compute covers the publish->detect latency. Poll-chain
// transitively bounds skew; 4-deep tag parity makes overwrites safe.
template <int EMB16>
__global__ __launch_bounds__(256, 1) void lstm_k(
    const f16* __restrict__ W16, const float* __restrict__ bias,
    const int* __restrict__ text, const float* __restrict__ embedf,
    const f16* __restrict__ embed16, const float* __restrict__ mask,
    float* __restrict__ out, u32* __restrict__ hx) {
  __shared__ __align__(16) f16 x_sw[2 * 4 * TBUF];  // [slot2][chain4] 67.6 KB
  __shared__ __align__(16) f16 h_sw[4 * 2 * TBUF];  // [chain4][par2] 67.6 KB

  const int tid = threadIdx.x;
  const int gl = blockIdx.x & 1;    // glset (32 batches)
  const int myq = blockIdx.x >> 1;  // 64-dim quarter

  const int wv = tid >> 6, l = tid & 63;
  const int kg = l >> 4, c16 = l & 15;
  const int jloc = wv * 16 + c16;   // dim within quarter
  const int jg = myq * 64 + jloc;   // global dim

  // staging mapping: 32 rows x 8 threads x 32 dims
  const int sr = tid >> 3, sc = sr >> 3, sb = sr & 7;
  const int sd = (tid & 7) * 32;
  const size_t strow = (size_t)(gl * 32 + sc * 8 + sb) * S_LEN;

  // poll mapping: thread -> (batch pb, u64-slot pw) x 3 partner quarters
  const int pb = tid >> 5, pw = tid & 31;
  const int qa = 0 + (0 >= myq), qb = 1 + (1 >= myq), qc = 2 + (2 >= myq);

  // zero LDS (pad rows 8..15 of every tile must stay zero)
  {
    f16x8 z = {(f16)0.f, (f16)0.f, (f16)0.f, (f16)0.f,
               (f16)0.f, (f16)0.f, (f16)0.f, (f16)0.f};
    for (int i = tid * 8; i < 2 * 4 * TBUF; i += 2048) *(f16x8*)&x_sw[i] = z;
    for (int i = tid * 8; i < 4 * 2 * TBUF; i += 2048) *(f16x8*)&h_sw[i] = z;
  }

  const float bi0 = bias[jg], bi1 = bias[256 + jg];
  const float bi2 = bias[512 + jg], bi3 = bias[768 + jg];

  float cc0[4] = {0.f, 0.f, 0.f, 0.f}, cc1[4] = {0.f, 0.f, 0.f, 0.f};
  float cc2[4] = {0.f, 0.f, 0.f, 0.f}, cc3[4] = {0.f, 0.f, 0.f, 0.f};
  float mm0[4] = {0.f, 0.f, 0.f, 0.f}, mm1[4] = {0.f, 0.f, 0.f, 0.f};
  float mm2[4] = {0.f, 0.f, 0.f, 0.f}, mm3[4] = {0.f, 0.f, 0.f, 0.f};
  if (kg < 2) {
#pragma unroll
    for (int i = 0; i < 4; i++) {
      mm0[i] = mask[(size_t)(gl * 32 + 0 + kg * 4 + i) * S_LEN];
      mm1[i] = mask[(size_t)(gl * 32 + 8 + kg * 4 + i) * S_LEN];
      mm2[i] = mask[(size_t)(gl * 32 + 16 + kg * 4 + i) * S_LEN];
      mm3[i] = mask[(size_t)(gl * 32 + 24 + kg * 4 + i) * S_LEN];
    }
  }

  // resident W: barr[gate][kc], rows n = gate*256 + jg, k = kc*32 + kg*8
  f16x8 barr[4][16];
#pragma unroll
  for (int gg = 0; gg < 4; gg++) {
    const f16* w = W16 + (size_t)(gg * 256 + jg) * 512 + kg * 8;
#pragma unroll
    for (int kc = 0; kc < 16; kc++) barr[gg][kc] = *(const f16x8*)(w + kc * 32);
  }

  // x staging helpers (32 dims = 4 f16x8 per thread)
  f16x8 sx[4];
  int idx_r;
  auto ldx = [&](int idx) {
    if (EMB16) {
      const f16x8* ep = (const f16x8*)(embed16 + (size_t)idx * 256 + sd);
      sx[0] = ep[0]; sx[1] = ep[1]; sx[2] = ep[2]; sx[3] = ep[3];
    } else {
      const float4* ep = (const float4*)(embedf + (size_t)idx * 256 + sd);
#pragma unroll
      for (int j = 0; j < 4; j++) {
        float4 a = ep[2 * j], b = ep[2 * j + 1];
        sx[j] = (f16x8){(f16)a.x, (f16)a.y, (f16)a.z, (f16)a.w,
                        (f16)b.x, (f16)b.y, (f16)b.z, (f16)b.w};
      }
    }
  };
  auto stx = [&](int slot) {
    f16* xb = &x_sw[(slot * 4 + sc) * TBUF + sb * HROW + sd];
    *(f16x8*)&xb[0] = sx[0];
    *(f16x8*)&xb[8] = sx[1];
    *(f16x8*)&xb[16] = sx[2];
    *(f16x8*)&xb[24] = sx[3];
  };

  auto xpart = [&](int c, int slot, f32x4 (&X)[4]) {
    const f16* xs = &x_sw[(slot * 4 + c) * TBUF];
    f32x4 t0 = {0.f, 0.f, 0.f, 0.f}, t1 = t0, t2 = t0, t3 = t0;
#pragma unroll
    for (int kc = 0; kc < 8; kc++) {
      f16x8 a = *(const f16x8*)&xs[c16 * HROW + kc * 32 + kg * 8];
      t0 = __builtin_amdgcn_mfma_f32_16x16x32_f16(a, barr[0][8 + kc], t0, 0, 0, 0);
      t1 = __builtin_amdgcn_mfma_f32_16x16x32_f16(a, barr[1][8 + kc], t1, 0, 0, 0);
      t2 = __builtin_amdgcn_mfma_f32_16x16x32_f16(a, barr[2][8 + kc], t2, 0, 0, 0);
      t3 = __builtin_amdgcn_mfma_f32_16x16x32_f16(a, barr[3][8 + kc], t3, 0, 0, 0);
    }
    X[0] = t0; X[1] = t1; X[2] = t2; X[3] = t3;
  };

  // prologue: slots 0,1 = x[0],x[1]; sx = x[2]; idx_r = text[3]
  ldx(text[strow + 0]); stx(0);
  ldx(text[strow + 1]); stx(1);
  ldx(text[strow + 2]);
  idx_r = text[strow + 3];
  __syncthreads();

  f32x4 XC0[4], XC1[4], XC2[4], XC3[4];
  xpart(0, 0, XC0); xpart(1, 0, XC1); xpart(2, 0, XC2); xpart(3, 0, XC3);

  auto phase = [&](int c, f32x4 (&X)[4], float (&cc)[4], float (&mm)[4], int t) {
    // poll chain c's tag-t data (published by partners at phase (t-1,c))
    if (t > 0) {
      const u64* hb = (const u64*)hx +
                      (((size_t)((t & 3) * 2 + gl) * 4 + c) * 1024) + pb * 128 + pw;
      u64 v1, v2, v3;
      int done;
      do {
        v1 = ld_hx64(hb + qa * 32);
        v2 = ld_hx64(hb + qb * 32);
        v3 = ld_hx64(hb + qc * 32);
        u32 mn = umin2(umin2(umin2((u32)v1, (u32)(v1 >> 32)),
                             umin2((u32)v2, (u32)(v2 >> 32))),
                       umin2((u32)v3, (u32)(v3 >> 32)));
        done = (int)((mn >> 16) == (u32)t);
      } while (!__all(done));
      f16* hd = &h_sw[(c * 2 + (t & 1)) * TBUF];
      *(u32*)&hd[pb * HROW + qa * 64 + pw * 2] =
          __builtin_amdgcn_perm((u32)(v1 >> 32), (u32)v1, PERM_SEL);
      *(u32*)&hd[pb * HROW + qb * 64 + pw * 2] =
          __builtin_amdgcn_perm((u32)(v2 >> 32), (u32)v2, PERM_SEL);
      *(u32*)&hd[pb * HROW + qc * 64 + pw * 2] =
          __builtin_amdgcn_perm((u32)(v3 >> 32), (u32)v3, PERM_SEL);
    }
    __syncthreads();

    // h-part MFMA for chain c (A rows 8..15 are zero pad)
    const f16* hs = &h_sw[(c * 2 + (t & 1)) * TBUF];
    f32x4 a0 = X[0], a1 = X[1], a2 = X[2], a3 = X[3];
#pragma unroll
    for (int kc = 0; kc < 8; kc++) {
      f16x8 a = *(const f16x8*)&hs[c16 * HROW + kc * 32 + kg * 8];
      a0 = __builtin_amdgcn_mfma_f32_16x16x32_f16(a, barr[0][kc], a0, 0, 0, 0);
      a1 = __builtin_amdgcn_mfma_f32_16x16x32_f16(a, barr[1][kc], a1, 0, 0, 0);
      a2 = __builtin_amdgcn_mfma_f32_16x16x32_f16(a, barr[2][kc], a2, 0, 0, 0);
      a3 = __builtin_amdgcn_mfma_f32_16x16x32_f16(a, barr[3][kc], a3, 0, 0, 0);
    }

    // update + publish: D rows 0..7 live in lanes kg<2 (row = kg*4 + i)
    if (kg < 2) {
      const u32 tagv = (u32)(t + 1);
      u32* hp = hx + (((size_t)(((t + 1) & 3) * 2 + gl) * 4 + c) * 2048) +
                myq * 64 + jloc;
      f16* hd2 = &h_sw[(c * 2 + ((t + 1) & 1)) * TBUF];
      float hv[4];
#pragma unroll
      for (int i = 0; i < 4; i++) {  // publish ASAP
        float gi = a0[i] + bi0, gf = a1[i] + bi1;
        float gG = a2[i] + bi2, go = a3[i] + bi3;
        cc[i] = sigf(gf) * cc[i] + sigf(gi) * tanh_fast(gG);
        hv[i] = sigf(go) * tanh_fast(cc[i]);
        st_hx(hp + (kg * 4 + i) * 256,
              (tagv << 16) | (u32)__builtin_bit_cast(unsigned short, (f16)hv[i]));
      }
#pragma unroll
      for (int i = 0; i < 4; i++) {
        int b = kg * 4 + i;
        out[((size_t)(gl * 32 + c * 8 + b) * S_LEN + t) * 256 + jg] = hv[i] * mm[i];
        hd2[b * HROW + jg] = (f16)hv[i];
        if (t + 1 < S_LEN)
          mm[i] = mask[(size_t)(gl * 32 + c * 8 + b) * S_LEN + (t + 1)];
      }
    }

    // window: RTT-hiding work for the next phases
    if (c == 0 && t + 2 < S_LEN) stx(t & 1);      // write x[t+2] (slot t&1 free)
    if (c == 1 && t + 3 < S_LEN) ldx(idx_r);      // load x[t+3]
    if (c == 2 && t + 4 < S_LEN) idx_r = text[strow + t + 4];
    if (t + 1 < S_LEN) xpart(c, (t + 1) & 1, X);  // xacc for (t+1, c)
  };

  for (int t = 0; t < S_LEN; t++) {
    phase(0, XC0, cc0, mm0, t);
    phase(1, XC1, cc1, mm1, t);
    phase(2, XC2, cc2, mm2, t);
    phase(3, XC3, cc3, mm3, t);
  }
}

extern "C" void kernel_launch(void* const* d_in, const int* in_sizes, int n_in,
                              void* d_out, int out_size, void* d_ws, size_t ws_size,
                              hipStream_t stream) {
  const int* text = (const int*)d_in[0];
  const float* mask = (const float*)d_in[1];
  // d_in[2] = len_seq: sort + inverse-sort is a no-op -> unused
  const float* embed = (const float*)d_in[3];
  const float* Wih = (const float*)d_in[4];
  const float* Whh = (const float*)d_in[5];
  const float* bih = (const float*)d_in[6];
  const float* bhh = (const float*)d_in[7];
  float* out = (float*)d_out;

  char* ws = (char*)d_ws;
  f16* W16 = (f16*)ws;                   // 1,048,576 B
  float* bias = (float*)(ws + 1048576);  // 4,096 B
  u32* hx = (u32*)(ws + 1052672);        // 262,144 B (4-deep x 2gl x 4c x 8b x 256)
  f16* embed16 = (f16*)(ws + 1314816);   // 16,384,000 B
  const size_t WS_NEED = 1314816 + 16384000;

  convert_k<<<2048, 256, 0, stream>>>(Wih, Whh, bih, bhh, W16, bias, hx);
  if (ws_size >= WS_NEED) {
    convert_embed_k<<<4000, 256, 0, stream>>>(embed, embed16);
    lstm_k<1><<<8, 256, 0, stream>>>(W16, bias, text, embed, embed16, mask, out, hx);
  } else {
    lstm_k<0><<<8, 256, 0, stream>>>(W16, bias, text, embed, embed16, mask, out, hx);
  }
}

// Round 9
// 5915.127 us; speedup vs baseline: 4.3425x; 4.3425x over previous
//
#include <hip/hip_runtime.h>

#define S_LEN 2048
#define HROW 264  // padded LDS row stride (f16): 528B = 4 banks offset/row

typedef _Float16 f16;
typedef _Float16 f16x8 __attribute__((ext_vector_type(8)));
typedef float f32x4 __attribute__((ext_vector_type(4)));
typedef unsigned u32;
typedef unsigned long long u64;

__device__ __forceinline__ float sigf(float x) {
  x = fminf(fmaxf(x, -30.f), 30.f);
  float e = __builtin_amdgcn_exp2f(-1.44269504089f * x);
  return __builtin_amdgcn_rcpf(1.f + e);
}
__device__ __forceinline__ float tanh_fast(float x) {
  x = fminf(fmaxf(x, -15.f), 15.f);
  float e = __builtin_amdgcn_exp2f(2.88539008178f * x);  // e^(2x)
  return 1.f - 2.f * __builtin_amdgcn_rcpf(e + 1.f);
}
__device__ __forceinline__ void st_hx(u32* p, u32 v) {
  __hip_atomic_store(p, v, __ATOMIC_RELAXED, __HIP_MEMORY_SCOPE_AGENT);
}
__device__ __forceinline__ u32 ld_hx(const u32* p) {
  return __hip_atomic_load(p, __ATOMIC_RELAXED, __HIP_MEMORY_SCOPE_AGENT);
}
__device__ __forceinline__ float swz8(float v) {
  int r = __builtin_amdgcn_ds_swizzle(__builtin_bit_cast(int, v), 0x201F);  // lane ^= 8
  return __builtin_bit_cast(float, r);
}
__device__ __forceinline__ u32 umin2(u32 a, u32 b) { return a < b ? a : b; }

// Build W16[1024][512] = [Whh | Wih] f16, bias = bih + bhh, zero hx tag words.
__global__ void convert_k(const float* __restrict__ Wih, const float* __restrict__ Whh,
                          const float* __restrict__ bih, const float* __restrict__ bhh,
                          f16* __restrict__ W16, float* __restrict__ bias,
                          u32* __restrict__ hx) {
  int i = blockIdx.x * blockDim.x + threadIdx.x;  // 524288 threads
  int n = i >> 9, k = i & 511;
  W16[i] = (f16)((k < 256) ? Whh[n * 256 + k] : Wih[n * 256 + (k - 256)]);
  if (i < 1024) bias[i] = bih[i] + bhh[i];
  if (i < 65536) hx[i] = 0u;  // 4-deep tag buffers; replay safety
}

// Pre-convert embedding table to f16 (8,192,000 elems, 8 per thread).
__global__ void convert_embed_k(const float* __restrict__ e, f16* __restrict__ e16) {
  int i = (blockIdx.x * 256 + threadIdx.x) * 8;
  float4 a = *(const float4*)(e + i);
  float4 b = *(const float4*)(e + i + 4);
  f16x8 v = {(f16)a.x, (f16)a.y, (f16)a.z, (f16)a.w,
             (f16)b.x, (f16)b.y, (f16)b.z, (f16)b.w};
  *(f16x8*)(e16 + i) = v;
}

// Persistent LSTM = r3 structure + 2 staggered chains + prefetched polls.
// 32 active wgs (of 64; blockIdx&7>=4 exit so the 8 partner wgs of a group
// share blockIdx%8 -> same XCD). wg = (gl, slice): serves groups G=2gl,2gl+1
// (8 batches each) for dims slice*32..+31. W-slice resident (barr0/barr1,
// shared by both chains). Per t: phase(c0) then phase(c1); each phase FIRST
// issues the other chain's 7 poll loads (named reg set -> latency hidden by
// this phase's compute), then checks its own prefetched set, gathers, one
// barrier, 16 h-MFMA, swz8 gate exchange, update, publish tag t+1, 16 x-MFMA
// for t+1. M-pad rows 8..15 of tiles are garbage (only D rows 0..7 are read)
// so tiles overlap at 8-row stride.
template <int EMB16>
__global__ __launch_bounds__(256, 1) void lstm_k(
    const f16* __restrict__ W16, const float* __restrict__ bias,
    const int* __restrict__ text, const float* __restrict__ embedf,
    const f16* __restrict__ embed16, const float* __restrict__ mask,
    float* __restrict__ out, u32* __restrict__ hx) {
  __shared__ __align__(16) f16 x_sw[72 * HROW];  // [chain2][slot4] 8-row tiles + 8 pad
  __shared__ __align__(16) f16 h_sw[40 * HROW];  // [chain2][par2] 8-row tiles + 8 pad

  const int gl = blockIdx.x & 7;
  const int slice = blockIdx.x >> 3;
  if (gl >= 4) return;
  const int j0 = slice * 32;
  const int tid = threadIdx.x;

  const int wv = tid >> 6, l = tid & 63;
  const int kg = l >> 4, c16 = l & 15;
  const int gsel = c16 >> 3, d3 = c16 & 7;
  const int jloc = wv * 8 + d3, jg = j0 + jloc;

  // staging mapping: thread -> (chain cs, batch bs, 16 dims at sd)
  const int cs = tid >> 7, bs = (tid >> 4) & 7, sd = (tid & 15) * 16;
  const size_t strow = (size_t)((gl * 2 + cs) * 8 + bs) * S_LEN;

  // poll mapping: thread -> (batch pbat, dim pjl) x 7 partner slices
  const int pbat = tid >> 5, pjl = tid & 31;
  int po[7];
#pragma unroll
  for (int k = 0; k < 7; k++) po[k] = (k + (k >= slice)) * 256;  // word offsets

  // zero h tiles (t=0 reads zeros; pad rows = don't-care)
  {
    f16x8 z = {(f16)0.f, (f16)0.f, (f16)0.f, (f16)0.f,
               (f16)0.f, (f16)0.f, (f16)0.f, (f16)0.f};
    for (int i = tid * 8; i < 40 * HROW; i += 2048) *(f16x8*)&h_sw[i] = z;
  }

  const float bi = bias[jg], bf = bias[256 + jg];
  const float bg_ = bias[512 + jg], bo = bias[768 + jg];

  const int upd = (kg < 2);
  const int batchA = kg * 4 + gsel * 2;
  const int batchB = batchA + 1;

  // resident weights: tile0 = gate gsel, tile1 = gate 2+gsel; K=512
  f16x8 barr0[16], barr1[16];
  {
    const f16* w0 = W16 + (size_t)(gsel * 256 + jg) * 512 + kg * 8;
    const f16* w1 = W16 + (size_t)((2 + gsel) * 256 + jg) * 512 + kg * 8;
#pragma unroll
    for (int kc = 0; kc < 16; kc++) {
      barr0[kc] = *(const f16x8*)(w0 + kc * 32);
      barr1[kc] = *(const f16x8*)(w1 + kc * 32);
    }
  }

  float ccA0 = 0.f, ccB0 = 0.f, ccA1 = 0.f, ccB1 = 0.f;
  float mA0 = 0.f, mB0 = 0.f, mA1 = 0.f, mB1 = 0.f;
  if (upd) {
    mA0 = mask[(size_t)((gl * 2 + 0) * 8 + batchA) * S_LEN];
    mB0 = mask[(size_t)((gl * 2 + 0) * 8 + batchB) * S_LEN];
    mA1 = mask[(size_t)((gl * 2 + 1) * 8 + batchA) * S_LEN];
    mB1 = mask[(size_t)((gl * 2 + 1) * 8 + batchB) * S_LEN];
  }

  // x staging (16 dims/thread)
  f16x8 sxa, sxb;
  int idx_r;
  auto ldx = [&](int idx) {
    if (EMB16) {
      const f16x8* ep = (const f16x8*)(embed16 + (size_t)idx * 256 + sd);
      sxa = ep[0];
      sxb = ep[1];
    } else {
      const float4* ep = (const float4*)(embedf + (size_t)idx * 256 + sd);
      float4 a = ep[0], b = ep[1], c = ep[2], d = ep[3];
      sxa = (f16x8){(f16)a.x, (f16)a.y, (f16)a.z, (f16)a.w,
                    (f16)b.x, (f16)b.y, (f16)b.z, (f16)b.w};
      sxb = (f16x8){(f16)c.x, (f16)c.y, (f16)c.z, (f16)c.w,
                    (f16)d.x, (f16)d.y, (f16)d.z, (f16)d.w};
    }
  };
  auto stx = [&](int slot) {
    f16* xb = &x_sw[((cs * 4 + slot) * 8 + bs) * HROW + sd];
    *(f16x8*)&xb[0] = sxa;
    *(f16x8*)&xb[8] = sxb;
  };

  auto xpart = [&](int c, int slot, f32x4& X0, f32x4& X1) {
    const f16* xs = &x_sw[(c * 4 + slot) * 8 * HROW];
    f32x4 t0 = {0.f, 0.f, 0.f, 0.f}, t1 = t0;
#pragma unroll
    for (int kc = 0; kc < 8; kc++) {
      f16x8 a = *(const f16x8*)&xs[c16 * HROW + kc * 32 + kg * 8];
      t0 = __builtin_amdgcn_mfma_f32_16x16x32_f16(a, barr0[8 + kc], t0, 0, 0, 0);
      t1 = __builtin_amdgcn_mfma_f32_16x16x32_f16(a, barr1[8 + kc], t1, 0, 0, 0);
    }
    X0 = t0;
    X1 = t1;
  };

  // two named poll-register sets (chain0 = q*, chain1 = r*) -- rule #20 safe
  u32 q0, q1, q2, q3, q4, q5, q6;
  u32 r0, r1, r2, r3, r4, r5, r6;
  auto pollbase = [&](int c, int tag) -> const u32* {
    return hx + ((size_t)((tag & 3) * 8 + (gl * 2 + c)) * 8) * 256 + pbat * 32 + pjl;
  };
  auto issue0 = [&](int tag) {
    const u32* hb = pollbase(0, tag);
    q0 = ld_hx(hb + po[0]); q1 = ld_hx(hb + po[1]); q2 = ld_hx(hb + po[2]);
    q3 = ld_hx(hb + po[3]); q4 = ld_hx(hb + po[4]); q5 = ld_hx(hb + po[5]);
    q6 = ld_hx(hb + po[6]);
  };
  auto issue1 = [&](int tag) {
    const u32* hb = pollbase(1, tag);
    r0 = ld_hx(hb + po[0]); r1 = ld_hx(hb + po[1]); r2 = ld_hx(hb + po[2]);
    r3 = ld_hx(hb + po[3]); r4 = ld_hx(hb + po[4]); r5 = ld_hx(hb + po[5]);
    r6 = ld_hx(hb + po[6]);
  };
  auto check0 = [&](int tag) {
    const u32* hb = pollbase(0, tag);
    while (true) {
      u32 mn = umin2(umin2(umin2(q0, q1), umin2(q2, q3)), umin2(umin2(q4, q5), q6));
      if (__all((int)((mn >> 16) == (u32)tag))) break;
      q0 = ld_hx(hb + po[0]); q1 = ld_hx(hb + po[1]); q2 = ld_hx(hb + po[2]);
      q3 = ld_hx(hb + po[3]); q4 = ld_hx(hb + po[4]); q5 = ld_hx(hb + po[5]);
      q6 = ld_hx(hb + po[6]);
    }
    f16* hd = &h_sw[(0 * 2 + (tag & 1)) * 8 * HROW];
    hd[pbat * HROW + (po[0] >> 3) + pjl] = __builtin_bit_cast(f16, (unsigned short)(q0 & 0xffffu));
    hd[pbat * HROW + (po[1] >> 3) + pjl] = __builtin_bit_cast(f16, (unsigned short)(q1 & 0xffffu));
    hd[pbat * HROW + (po[2] >> 3) + pjl] = __builtin_bit_cast(f16, (unsigned short)(q2 & 0xffffu));
    hd[pbat * HROW + (po[3] >> 3) + pjl] = __builtin_bit_cast(f16, (unsigned short)(q3 & 0xffffu));
    hd[pbat * HROW + (po[4] >> 3) + pjl] = __builtin_bit_cast(f16, (unsigned short)(q4 & 0xffffu));
    hd[pbat * HROW + (po[5] >> 3) + pjl] = __builtin_bit_cast(f16, (unsigned short)(q5 & 0xffffu));
    hd[pbat * HROW + (po[6] >> 3) + pjl] = __builtin_bit_cast(f16, (unsigned short)(q6 & 0xffffu));
  };
  auto check1 = [&](int tag) {
    const u32* hb = pollbase(1, tag);
    while (true) {
      u32 mn = umin2(umin2(umin2(r0, r1), umin2(r2, r3)), umin2(umin2(r4, r5), r6));
      if (__all((int)((mn >> 16) == (u32)tag))) break;
      r0 = ld_hx(hb + po[0]); r1 = ld_hx(hb + po[1]); r2 = ld_hx(hb + po[2]);
      r3 = ld_hx(hb + po[3]); r4 = ld_hx(hb + po[4]); r5 = ld_hx(hb + po[5]);
      r6 = ld_hx(hb + po[6]);
    }
    f16* hd = &h_sw[(1 * 2 + (tag & 1)) * 8 * HROW];
    hd[pbat * HROW + (po[0] >> 3) + pjl] = __builtin_bit_cast(f16, (unsigned short)(r0 & 0xffffu));
    hd[pbat * HROW + (po[1] >> 3) + pjl] = __builtin_bit_cast(f16, (unsigned short)(r1 & 0xffffu));
    hd[pbat * HROW + (po[2] >> 3) + pjl] = __builtin_bit_cast(f16, (unsigned short)(r2 & 0xffffu));
    hd[pbat * HROW + (po[3] >> 3) + pjl] = __builtin_bit_cast(f16, (unsigned short)(r3 & 0xffffu));
    hd[pbat * HROW + (po[4] >> 3) + pjl] = __builtin_bit_cast(f16, (unsigned short)(r4 & 0xffffu));
    hd[pbat * HROW + (po[5] >> 3) + pjl] = __builtin_bit_cast(f16, (unsigned short)(r5 & 0xffffu));
    hd[pbat * HROW + (po[6] >> 3) + pjl] = __builtin_bit_cast(f16, (unsigned short)(r6 & 0xffffu));
  };

  // prologue: slots 0,1 = x[0],x[1]; sx = x[2]; idx_r = text[3]
  ldx(text[strow + 0]); stx(0);
  ldx(text[strow + 1]); stx(1);
  ldx(text[strow + 2]);
  idx_r = text[strow + 3];
  __syncthreads();

  f32x4 XA0, XA1, XB0, XB1;
  xpart(0, 0, XA0, XA1);
  xpart(1, 0, XB0, XB1);

  auto phase = [&](int c, int t, f32x4& X0, f32x4& X1, float& ccA, float& ccB,
                   float& mA, float& mB) {
    // 1) prefetch the OTHER chain's poll loads (checked next phase)
    const int tgt = (c == 0) ? t : t + 1;
    if (tgt >= 1 && tgt < S_LEN) {
      if (c == 0) issue1(tgt);
      else issue0(tgt);
    }
    // 2) check own prefetched set, gather to LDS
    if (t > 0) {
      if (c == 0) check0(t);
      else check1(t);
    }
    __syncthreads();

    // 3) h-part MFMA (critical)
    const f16* hs = &h_sw[(c * 2 + (t & 1)) * 8 * HROW];
    f32x4 acc0 = X0, acc1 = X1;
#pragma unroll
    for (int kc = 0; kc < 8; kc++) {
      f16x8 a = *(const f16x8*)&hs[c16 * HROW + kc * 32 + kg * 8];
      acc0 = __builtin_amdgcn_mfma_f32_16x16x32_f16(a, barr0[kc], acc0, 0, 0, 0);
      acc1 = __builtin_amdgcn_mfma_f32_16x16x32_f16(a, barr1[kc], acc1, 0, 0, 0);
    }

    // 4) in-wave gate exchange (lane d <-> d^8)
    float a0_0 = acc0[0], a0_1 = acc0[1], a0_2 = acc0[2], a0_3 = acc0[3];
    float a1_0 = acc1[0], a1_1 = acc1[1], a1_2 = acc1[2], a1_3 = acc1[3];
    float o0_0 = swz8(a0_0), o0_1 = swz8(a0_1), o0_2 = swz8(a0_2), o0_3 = swz8(a0_3);
    float o1_0 = swz8(a1_0), o1_1 = swz8(a1_1), o1_2 = swz8(a1_2), o1_3 = swz8(a1_3);

    const int G = gl * 2 + c;
    f16* hd2 = &h_sw[(c * 2 + ((t + 1) & 1)) * 8 * HROW];
    if (upd) {
      float giA = (gsel ? o0_2 : a0_0) + bi;
      float gfA = (gsel ? a0_2 : o0_0) + bf;
      float ggA = (gsel ? o1_2 : a1_0) + bg_;
      float goA = (gsel ? a1_2 : o1_0) + bo;
      float giB = (gsel ? o0_3 : a0_1) + bi;
      float gfB = (gsel ? a0_3 : o0_1) + bf;
      float ggB = (gsel ? o1_3 : a1_1) + bg_;
      float goB = (gsel ? a1_3 : o1_1) + bo;

      ccA = sigf(gfA) * ccA + sigf(giA) * tanh_fast(ggA);
      float hA = sigf(goA) * tanh_fast(ccA);
      ccB = sigf(gfB) * ccB + sigf(giB) * tanh_fast(ggB);
      float hB = sigf(goB) * tanh_fast(ccB);

      const u32 tagv = (u32)(t + 1);
      u32* hbp = hx + ((size_t)((tagv & 3) * 8 + G) * 8 + slice) * 256 + batchA * 32 + jloc;
      st_hx(hbp, (tagv << 16) | (u32)__builtin_bit_cast(unsigned short, (f16)hA));
      st_hx(hbp + 32, (tagv << 16) | (u32)__builtin_bit_cast(unsigned short, (f16)hB));

      const size_t rowA = (size_t)(G * 8 + batchA) * S_LEN;
      const size_t rowB = (size_t)(G * 8 + batchB) * S_LEN;
      out[(rowA + t) * 256 + jg] = hA * mA;
      out[(rowB + t) * 256 + jg] = hB * mB;
      hd2[batchA * HROW + jg] = (f16)hA;
      hd2[batchB * HROW + jg] = (f16)hB;
      if (t + 1 < S_LEN) {
        mA = mask[rowA + t + 1];
        mB = mask[rowB + t + 1];
      }
    }

    // 5) staggered window work
    if (c == 0) {
      if (t + 2 < S_LEN) stx((t + 2) & 3);  // write x[t+2]
    } else {
      if (t + 3 < S_LEN) ldx(idx_r);        // load x[t+3]
      if (t + 4 < S_LEN) idx_r = text[strow + t + 4];
    }
    if (t + 1 < S_LEN) xpart(c, (t + 1) & 3, X0, X1);  // xacc for t+1
  };

  for (int t = 0; t < S_LEN; t++) {
    phase(0, t, XA0, XA1, ccA0, ccB0, mA0, mB0);
    phase(1, t, XB0, XB1, ccA1, ccB1, mA1, mB1);
  }
}

extern "C" void kernel_launch(void* const* d_in, const int* in_sizes, int n_in,
                              void* d_out, int out_size, void* d_ws, size_t ws_size,
                              hipStream_t stream) {
  const int* text = (const int*)d_in[0];
  const float* mask = (const float*)d_in[1];
  // d_in[2] = len_seq: sort + inverse-sort is a no-op -> unused
  const float* embed = (const float*)d_in[3];
  const float* Wih = (const float*)d_in[4];
  const float* Whh = (const float*)d_in[5];
  const float* bih = (const float*)d_in[6];
  const float* bhh = (const float*)d_in[7];
  float* out = (float*)d_out;

  char* ws = (char*)d_ws;
  f16* W16 = (f16*)ws;                   // 1,048,576 B
  float* bias = (float*)(ws + 1048576);  // 4,096 B
  u32* hx = (u32*)(ws + 1052672);        // 262,144 B (4 dep x 8 G x 8 slice x 256)
  f16* embed16 = (f16*)(ws + 1314816);   // 16,384,000 B
  const size_t WS_NEED = 1314816 + 16384000;

  convert_k<<<2048, 256, 0, stream>>>(Wih, Whh, bih, bhh, W16, bias, hx);
  if (ws_size >= WS_NEED) {
    convert_embed_k<<<4000, 256, 0, stream>>>(embed, embed16);
    lstm_k<1><<<64, 256, 0, stream>>>(W16, bias, text, embed, embed16, mask, out, hx);
  } else {
    lstm_k<0><<<64, 256, 0, stream>>>(W16, bias, text, embed, embed16, mask, out, hx);
  }
}